// Round 1
// baseline (120.386 us; speedup 1.0000x reference)
//
#include <hip/hip_runtime.h>

#define BB 32
#define SS 2048
#define DD 1024

#if defined(__has_builtin)
#  if __has_builtin(__builtin_amdgcn_exp2f)
#    define EXP2F(x) __builtin_amdgcn_exp2f(x)
#  endif
#  if __has_builtin(__builtin_amdgcn_rcpf)
#    define RCPF(x) __builtin_amdgcn_rcpf(x)
#  endif
#endif
#ifndef EXP2F
#  define EXP2F(x) exp2f(x)
#endif
#ifndef RCPF
#  define RCPF(x) (1.0f / (x))
#endif

#define LOG2E 1.44269504088896340736f

__device__ __forceinline__ float fast_tanh(float x) {
    // tanh(x) = (e^{2x}-1)/(e^{2x}+1); e^{2x} = 2^{2x*log2(e)}
    x = fminf(fmaxf(x, -20.0f), 20.0f);
    float e = EXP2F(x * (2.0f * LOG2E));
    return (e - 1.0f) * RCPF(e + 1.0f);
}

// ---------------- K1: dec_feature = dec_hidden @ W^T + b ----------------
// one wave per output element (b,i); 8192 blocks x 256 threads (4 waves)
__global__ __launch_bounds__(256) void k_decfeat(
    const float* __restrict__ dh, const float* __restrict__ W,
    const float* __restrict__ bd, float* __restrict__ df) {
    int wave = threadIdx.x >> 6;
    int lane = threadIdx.x & 63;
    int o = blockIdx.x * 4 + wave;          // 0 .. 32767
    int b = o >> 10, i = o & 1023;
    const float4* wrow = (const float4*)(W + (size_t)i * DD);
    const float4* drow = (const float4*)(dh + (size_t)b * DD);
    float acc = 0.0f;
#pragma unroll
    for (int r = 0; r < 4; ++r) {
        float4 w4 = wrow[lane + 64 * r];
        float4 d4 = drow[lane + 64 * r];
        acc += w4.x * d4.x + w4.y * d4.y + w4.z * d4.z + w4.w * d4.w;
    }
#pragma unroll
    for (int off = 32; off; off >>= 1) acc += __shfl_down(acc, off, 64);
    if (lane == 0) df[o] = acc + bd[i];
}

// ---------------- K2: score[b,s] = v . tanh(ef + df + cov*wc) ----------------
// block handles one b and 8 consecutive s rows; thread t owns float4 granule t of D
__global__ __launch_bounds__(256) void k_score(
    const float* __restrict__ ef, const float* __restrict__ df,
    const float* __restrict__ cov, const float* __restrict__ v,
    const float* __restrict__ wc, float* __restrict__ score) {
    int b  = blockIdx.x >> 8;               // 256 tiles per batch
    int s0 = (blockIdx.x & 255) * 8;
    int t  = threadIdx.x;
    float4 v4 = ((const float4*)v)[t];
    float4 w4 = ((const float4*)wc)[t];
    float4 d4 = ((const float4*)(df + (size_t)b * DD))[t];
    float part[8];
#pragma unroll
    for (int k = 0; k < 8; ++k) {
        int s = s0 + k;
        float c = cov[b * SS + s];
        float4 e4 = ((const float4*)(ef + ((size_t)b * SS + s) * DD))[t];
        float t0 = fast_tanh(e4.x + d4.x + c * w4.x);
        float t1 = fast_tanh(e4.y + d4.y + c * w4.y);
        float t2 = fast_tanh(e4.z + d4.z + c * w4.z);
        float t3 = fast_tanh(e4.w + d4.w + c * w4.w);
        part[k] = v4.x * t0 + v4.y * t1 + v4.z * t2 + v4.w * t3;
    }
    __shared__ float red[4][8];
    int lane = t & 63, wave = t >> 6;
#pragma unroll
    for (int k = 0; k < 8; ++k) {
        float p = part[k];
#pragma unroll
        for (int off = 32; off; off >>= 1) p += __shfl_down(p, off, 64);
        if (lane == 0) red[wave][k] = p;
    }
    __syncthreads();
    if (t < 8) {
        score[b * SS + s0 + t] = red[0][t] + red[1][t] + red[2][t] + red[3][t];
    }
}

// ---------------- K3: softmax*mask renorm + coverage_new ----------------
// one block per batch; 256 threads x 8 elements each
__global__ __launch_bounds__(256) void k_softmax(
    const float* __restrict__ score, const float* __restrict__ mask,
    const float* __restrict__ cov, float* __restrict__ attn,
    float* __restrict__ covnew) {
    int b = blockIdx.x, t = threadIdx.x;
    int lane = t & 63, wave = t >> 6;
    __shared__ float redm[4], reds[4];
    float sc[8], mk[8];
    float m = -1e30f;
#pragma unroll
    for (int k = 0; k < 8; ++k) {
        int s = t + 256 * k;
        sc[k] = score[b * SS + s];
        mk[k] = mask[b * SS + s];
        m = fmaxf(m, sc[k]);
    }
#pragma unroll
    for (int off = 32; off; off >>= 1) m = fmaxf(m, __shfl_down(m, off, 64));
    if (lane == 0) redm[wave] = m;
    __syncthreads();
    m = fmaxf(fmaxf(redm[0], redm[1]), fmaxf(redm[2], redm[3]));
    float e[8];
    float sum = 0.0f;
#pragma unroll
    for (int k = 0; k < 8; ++k) {
        e[k] = EXP2F((sc[k] - m) * LOG2E) * mk[k];
        sum += e[k];
    }
#pragma unroll
    for (int off = 32; off; off >>= 1) sum += __shfl_down(sum, off, 64);
    if (lane == 0) reds[wave] = sum;
    __syncthreads();
    float inv = RCPF(reds[0] + reds[1] + reds[2] + reds[3]);
#pragma unroll
    for (int k = 0; k < 8; ++k) {
        int s = t + 256 * k;
        float a = e[k] * inv;
        attn[b * SS + s] = a;
        covnew[b * SS + s] = cov[b * SS + s] + a;
    }
}

// ---------------- K4: context partials over s-chunks ----------------
// 64 chunks of 32 s-rows; block = (b, chunk); thread t owns float4 granule t of D
__global__ __launch_bounds__(256) void k_ctx_part(
    const float* __restrict__ eo, const float* __restrict__ attn,
    float* __restrict__ part) {
    int b = blockIdx.x >> 6, ch = blockIdx.x & 63;
    int t = threadIdx.x;
    int s0 = ch * 32;
    const float4* base = (const float4*)(eo + ((size_t)b * SS + s0) * DD);
    float4 acc = make_float4(0.f, 0.f, 0.f, 0.f);
#pragma unroll 4
    for (int k = 0; k < 32; ++k) {
        float a = attn[b * SS + s0 + k];
        float4 e4 = base[(size_t)k * 256 + t];
        acc.x += a * e4.x; acc.y += a * e4.y;
        acc.z += a * e4.z; acc.w += a * e4.w;
    }
    ((float4*)part)[((size_t)b * 64 + ch) * 256 + t] = acc;
}

// ---------------- K5: reduce partials into context ----------------
__global__ __launch_bounds__(256) void k_ctx_reduce(
    const float* __restrict__ part, float* __restrict__ ctx) {
    int b = blockIdx.x, t = threadIdx.x;
    const float4* p = (const float4*)part + (size_t)b * 64 * 256 + t;
    float4 acc = make_float4(0.f, 0.f, 0.f, 0.f);
#pragma unroll 8
    for (int ch = 0; ch < 64; ++ch) {
        float4 e4 = p[(size_t)ch * 256];
        acc.x += e4.x; acc.y += e4.y; acc.z += e4.z; acc.w += e4.w;
    }
    ((float4*)ctx)[b * 256 + t] = acc;
}

extern "C" void kernel_launch(void* const* d_in, const int* in_sizes, int n_in,
                              void* d_out, int out_size, void* d_ws, size_t ws_size,
                              hipStream_t stream) {
    const float* dec_hidden = (const float*)d_in[0];
    const float* enc_output = (const float*)d_in[1];
    const float* enc_feature = (const float*)d_in[2];
    const float* enc_mask   = (const float*)d_in[3];
    // d_in[4] = sec_attn (unused by reference outputs)
    const float* coverage   = (const float*)d_in[5];
    const float* W_dec      = (const float*)d_in[6];
    const float* b_dec      = (const float*)d_in[7];
    const float* v          = (const float*)d_in[8];
    const float* w_cov      = (const float*)d_in[9];

    float* ctx    = (float*)d_out;                    // [B, DIM]   32768
    float* attn   = (float*)d_out + BB * DD;          // [B, S]     65536
    float* covnew = (float*)d_out + BB * DD + BB * SS;// [B, S]     65536

    char* ws = (char*)d_ws;
    float* df    = (float*)(ws);                       // 32*1024*4   = 128 KiB
    float* score = (float*)(ws + 131072);              // 32*2048*4   = 256 KiB
    float* part  = (float*)(ws + 131072 + 262144);     // 32*64*1024*4 = 8 MiB

    k_decfeat   <<<8192, 256, 0, stream>>>(dec_hidden, W_dec, b_dec, df);
    k_score     <<<8192, 256, 0, stream>>>(enc_feature, df, coverage, v, w_cov, score);
    k_softmax   <<<BB,   256, 0, stream>>>(score, enc_mask, coverage, attn, covnew);
    k_ctx_part  <<<BB*64,256, 0, stream>>>(enc_output, attn, part);
    k_ctx_reduce<<<BB,   256, 0, stream>>>(part, ctx);
}

// Round 2
// 101.773 us; speedup vs baseline: 1.1829x; 1.1829x over previous
//
#include <hip/hip_runtime.h>

#define BB 32
#define SS 2048
#define DD 1024

typedef float f32x4 __attribute__((ext_vector_type(4)));

#if defined(__has_builtin)
#  if __has_builtin(__builtin_amdgcn_exp2f)
#    define EXP2F(x) __builtin_amdgcn_exp2f(x)
#  endif
#  if __has_builtin(__builtin_amdgcn_rcpf)
#    define RCPF(x) __builtin_amdgcn_rcpf(x)
#  endif
#endif
#ifndef EXP2F
#  define EXP2F(x) exp2f(x)
#endif
#ifndef RCPF
#  define RCPF(x) (1.0f / (x))
#endif

#define LOG2E 1.44269504088896340736f

__device__ __forceinline__ float fast_tanh(float x) {
    x = fminf(fmaxf(x, -20.0f), 20.0f);
    float e = EXP2F(x * (2.0f * LOG2E));
    return (e - 1.0f) * RCPF(e + 1.0f);
}

__device__ __forceinline__ f32x4 ntload4(const float* p) {
    return __builtin_nontemporal_load((const f32x4*)p);
}

// ---------------- K1: dec_feature = dec_hidden @ W^T + b ----------------
__global__ __launch_bounds__(256) void k_decfeat(
    const float* __restrict__ dh, const float* __restrict__ W,
    const float* __restrict__ bd, float* __restrict__ df) {
    int wave = threadIdx.x >> 6;
    int lane = threadIdx.x & 63;
    int o = blockIdx.x * 4 + wave;          // 0 .. 32767
    int b = o >> 10, i = o & 1023;
    const float4* wrow = (const float4*)(W + (size_t)i * DD);
    const float4* drow = (const float4*)(dh + (size_t)b * DD);
    float acc = 0.0f;
#pragma unroll
    for (int r = 0; r < 4; ++r) {
        float4 w4 = wrow[lane + 64 * r];
        float4 d4 = drow[lane + 64 * r];
        acc += w4.x * d4.x + w4.y * d4.y + w4.z * d4.z + w4.w * d4.w;
    }
#pragma unroll
    for (int off = 32; off; off >>= 1) acc += __shfl_down(acc, off, 64);
    if (lane == 0) df[o] = acc + bd[i];
}

// ---------------- K2: score[b,s] = v . tanh(ef + df + cov*wc) ----------------
// block = (b, 8-row s-tile); thread t owns float4 granule t of D
__global__ __launch_bounds__(256) void k_score(
    const float* __restrict__ ef, const float* __restrict__ df,
    const float* __restrict__ cov, const float* __restrict__ v,
    const float* __restrict__ wc, float* __restrict__ score) {
    int b  = blockIdx.x >> 8;               // 256 tiles per batch
    int s0 = (blockIdx.x & 255) * 8;
    int t  = threadIdx.x;
    float4 v4 = ((const float4*)v)[t];
    float4 w4 = ((const float4*)wc)[t];
    float4 d4 = ((const float4*)(df + (size_t)b * DD))[t];
    float part[8];
#pragma unroll
    for (int k = 0; k < 8; ++k) {
        int s = s0 + k;
        float c = cov[b * SS + s];
        f32x4 e4 = ntload4(ef + ((size_t)b * SS + s) * DD + t * 4);
        float t0 = fast_tanh(e4.x + d4.x + c * w4.x);
        float t1 = fast_tanh(e4.y + d4.y + c * w4.y);
        float t2 = fast_tanh(e4.z + d4.z + c * w4.z);
        float t3 = fast_tanh(e4.w + d4.w + c * w4.w);
        part[k] = v4.x * t0 + v4.y * t1 + v4.z * t2 + v4.w * t3;
    }
    __shared__ float red[4][8];
    int lane = t & 63, wave = t >> 6;
#pragma unroll
    for (int k = 0; k < 8; ++k) {
        float p = part[k];
#pragma unroll
        for (int off = 32; off; off >>= 1) p += __shfl_down(p, off, 64);
        if (lane == 0) red[wave][k] = p;
    }
    __syncthreads();
    if (t < 8) {
        score[b * SS + s0 + t] = red[0][t] + red[1][t] + red[2][t] + red[3][t];
    }
}

// ---------------- K3: softmax*mask renorm + coverage_new ----------------
__global__ __launch_bounds__(256) void k_softmax(
    const float* __restrict__ score, const float* __restrict__ mask,
    const float* __restrict__ cov, float* __restrict__ attn,
    float* __restrict__ covnew) {
    int b = blockIdx.x, t = threadIdx.x;
    int lane = t & 63, wave = t >> 6;
    __shared__ float redm[4], reds[4];
    float sc[8], mk[8];
    float m = -1e30f;
#pragma unroll
    for (int k = 0; k < 8; ++k) {
        int s = t + 256 * k;
        sc[k] = score[b * SS + s];
        mk[k] = mask[b * SS + s];
        m = fmaxf(m, sc[k]);
    }
#pragma unroll
    for (int off = 32; off; off >>= 1) m = fmaxf(m, __shfl_down(m, off, 64));
    if (lane == 0) redm[wave] = m;
    __syncthreads();
    m = fmaxf(fmaxf(redm[0], redm[1]), fmaxf(redm[2], redm[3]));
    float e[8];
    float sum = 0.0f;
#pragma unroll
    for (int k = 0; k < 8; ++k) {
        e[k] = EXP2F((sc[k] - m) * LOG2E) * mk[k];
        sum += e[k];
    }
#pragma unroll
    for (int off = 32; off; off >>= 1) sum += __shfl_down(sum, off, 64);
    if (lane == 0) reds[wave] = sum;
    __syncthreads();
    float inv = RCPF(reds[0] + reds[1] + reds[2] + reds[3]);
#pragma unroll
    for (int k = 0; k < 8; ++k) {
        int s = t + 256 * k;
        float a = e[k] * inv;
        attn[b * SS + s] = a;
        covnew[b * SS + s] = cov[b * SS + s] + a;
    }
}

// ---------------- K4: context partials over 32 s-chunks of 64 rows ----------------
__global__ __launch_bounds__(256) void k_ctx_part(
    const float* __restrict__ eo, const float* __restrict__ attn,
    float* __restrict__ part) {
    int b = blockIdx.x >> 5, ch = blockIdx.x & 31;
    int t = threadIdx.x;
    int s0 = ch * 64;
    const float* base = eo + ((size_t)b * SS + s0) * DD;
    f32x4 acc = {0.f, 0.f, 0.f, 0.f};
#pragma unroll 8
    for (int k = 0; k < 64; ++k) {
        float a = attn[b * SS + s0 + k];
        f32x4 e4 = ntload4(base + (size_t)k * DD + t * 4);
        acc += a * e4;
    }
    ((f32x4*)part)[((size_t)b * 32 + ch) * 256 + t] = acc;
}

// ---------------- K5: reduce partials into context (wide: 256 blocks) ----------------
// block = (b, d-tile of 32 float4); 256 threads = 32 slots x 8 chunk-groups
__global__ __launch_bounds__(256) void k_ctx_reduce(
    const float* __restrict__ part, float* __restrict__ ctx) {
    int b = blockIdx.x >> 3, dt = blockIdx.x & 7;
    int t = threadIdx.x;
    int slot = t & 31, grp = t >> 5;
    int f4 = dt * 32 + slot;
    const f32x4* p = (const f32x4*)part;
    f32x4 acc = {0.f, 0.f, 0.f, 0.f};
#pragma unroll
    for (int j = 0; j < 4; ++j) {
        int ch = grp + 8 * j;
        acc += p[((size_t)b * 32 + ch) * 256 + f4];
    }
    __shared__ f32x4 red[8][32];
    red[grp][slot] = acc;
    __syncthreads();
    if (t < 32) {
        f32x4 s = red[0][t];
#pragma unroll
        for (int g = 1; g < 8; ++g) s += red[g][t];
        ((f32x4*)ctx)[(size_t)b * 256 + dt * 32 + t] = s;
    }
}

extern "C" void kernel_launch(void* const* d_in, const int* in_sizes, int n_in,
                              void* d_out, int out_size, void* d_ws, size_t ws_size,
                              hipStream_t stream) {
    const float* dec_hidden  = (const float*)d_in[0];
    const float* enc_output  = (const float*)d_in[1];
    const float* enc_feature = (const float*)d_in[2];
    const float* enc_mask    = (const float*)d_in[3];
    // d_in[4] = sec_attn (unused by reference outputs)
    const float* coverage    = (const float*)d_in[5];
    const float* W_dec       = (const float*)d_in[6];
    const float* b_dec       = (const float*)d_in[7];
    const float* v           = (const float*)d_in[8];
    const float* w_cov       = (const float*)d_in[9];

    float* ctx    = (float*)d_out;                     // [B, DIM]   32768
    float* attn   = (float*)d_out + BB * DD;           // [B, S]     65536
    float* covnew = (float*)d_out + BB * DD + BB * SS; // [B, S]     65536

    char* ws = (char*)d_ws;
    float* df    = (float*)(ws);                       // 128 KiB
    float* score = (float*)(ws + 131072);              // 256 KiB
    float* part  = (float*)(ws + 131072 + 262144);     // 32*32*1024*4 = 4 MiB

    k_decfeat   <<<8192,  256, 0, stream>>>(dec_hidden, W_dec, b_dec, df);
    k_score     <<<8192,  256, 0, stream>>>(enc_feature, df, coverage, v, w_cov, score);
    k_softmax   <<<BB,    256, 0, stream>>>(score, enc_mask, coverage, attn, covnew);
    k_ctx_part  <<<BB*32, 256, 0, stream>>>(enc_output, attn, part);
    k_ctx_reduce<<<BB*8,  256, 0, stream>>>(part, ctx);
}